// Round 1
// baseline (455.895 us; speedup 1.0000x reference)
//
#include <hip/hip_runtime.h>

// Fused MHA: X[4,2048,1024] fp32; W_K,W_Q,W_V,W_out[1024,1024]; b_out[1024].
// Pipeline (all bf16 MFMA, fp32 accum):
//   1. convert_x:  X fp32 -> Xb bf16
//   2. transpose_w: W* fp32 [k][n] -> Wt bf16 [n][k]  (B^T layout for MFMA B-frags)
//   3. gemm_qkv:   Q (scaled by 0.125), K  [8192][1024]; V stored transposed Vt[b*1024+n][s]
//   4. attn:       causal flash attention per (b,h,qtile), online softmax
//   5. gemm_out:   C @ W_out + b_out -> fp32 out

typedef float  f32x4  __attribute__((ext_vector_type(4)));
typedef __bf16 bf16x8 __attribute__((ext_vector_type(8)));

#define DIM   1024
#define SEQ   2048
#define HDIM  64
#define MTOT  8192

static __device__ __forceinline__ unsigned short f2bf(float f) {
  unsigned int u = __builtin_bit_cast(unsigned int, f);
  u += 0x7fffu + ((u >> 16) & 1u);   // RNE
  return (unsigned short)(u >> 16);
}

// async global->LDS, 16B per lane; lds dest must be wave-uniform base (+lane*16 implicit)
#define GLDS16(g, l)                                                                   \
  __builtin_amdgcn_global_load_lds((__attribute__((address_space(1))) void*)(g),       \
                                   (__attribute__((address_space(3))) void*)(l), 16, 0, 0)

__global__ __launch_bounds__(256) void convert_x(const float4* __restrict__ X,
                                                 ushort4* __restrict__ Xb) {
  int i = blockIdx.x * 256 + threadIdx.x;   // 8192*256*4 = 8388608 floats exactly
  float4 v = X[i];
  ushort4 o;
  o.x = f2bf(v.x); o.y = f2bf(v.y); o.z = f2bf(v.z); o.w = f2bf(v.w);
  Xb[i] = o;
}

__global__ __launch_bounds__(256) void transpose_w(const float* __restrict__ WQ,
                                                   const float* __restrict__ WK,
                                                   const float* __restrict__ WV,
                                                   const float* __restrict__ WO,
                                                   unsigned short* __restrict__ WtAll) {
  const int z = blockIdx.z;
  const float* W = (z == 0) ? WQ : (z == 1) ? WK : (z == 2) ? WV : WO;
  unsigned short* Wt = WtAll + (size_t)z * (DIM * DIM);
  __shared__ float tile[32][33];
  const int tx = threadIdx.x, ty = threadIdx.y;        // 32 x 8
  const int n0 = blockIdx.x * 32, k0 = blockIdx.y * 32;
#pragma unroll
  for (int r = 0; r < 4; ++r)
    tile[ty + 8 * r][tx] = W[(size_t)(k0 + ty + 8 * r) * DIM + n0 + tx];
  __syncthreads();
#pragma unroll
  for (int r = 0; r < 4; ++r)
    Wt[(size_t)(n0 + ty + 8 * r) * DIM + k0 + tx] = f2bf(tile[tx][ty + 8 * r]);
}

// ---- 128x128-tile bf16 GEMM (m97 structure), z selects Q/K/V ----
__global__ __launch_bounds__(256) void gemm_qkv(const unsigned short* __restrict__ Xb,
                                                const unsigned short* __restrict__ WtAll,
                                                unsigned short* __restrict__ Qb,
                                                unsigned short* __restrict__ Kb,
                                                unsigned short* __restrict__ Vtb) {
  const int z = blockIdx.z;
  const unsigned short* Wt = WtAll + (size_t)z * (DIM * DIM);
  const int m0 = blockIdx.x * 128, n0 = blockIdx.y * 128;
  const int lane = threadIdx.x & 63, wave = threadIdx.x >> 6;
  const int wr = wave >> 1, wc = wave & 1;
  const int l15 = lane & 15, lg = lane >> 4;
  const int rowA = lane >> 2, colA = (lane & 3) * 8;
  const int sA = wave * 2;
  __shared__ __align__(16) unsigned short As[128 * 32], Bs[128 * 32];
  f32x4 acc[4][4] = {};

  for (int kt = 0; kt < DIM; kt += 32) {
    GLDS16(Xb + (size_t)(m0 + (sA + 0) * 16 + rowA) * DIM + kt + colA, &As[(sA + 0) * 512]);
    GLDS16(Xb + (size_t)(m0 + (sA + 1) * 16 + rowA) * DIM + kt + colA, &As[(sA + 1) * 512]);
    GLDS16(Wt + (size_t)(n0 + (sA + 0) * 16 + rowA) * DIM + kt + colA, &Bs[(sA + 0) * 512]);
    GLDS16(Wt + (size_t)(n0 + (sA + 1) * 16 + rowA) * DIM + kt + colA, &Bs[(sA + 1) * 512]);
    asm volatile("s_waitcnt vmcnt(0)" ::: "memory");
    __syncthreads();
    bf16x8 af[4], bfr[4];
#pragma unroll
    for (int mi = 0; mi < 4; ++mi)
      af[mi] = *(const bf16x8*)&As[(wr * 64 + mi * 16 + l15) * 32 + lg * 8];
#pragma unroll
    for (int ni = 0; ni < 4; ++ni)
      bfr[ni] = *(const bf16x8*)&Bs[(wc * 64 + ni * 16 + l15) * 32 + lg * 8];
#pragma unroll
    for (int mi = 0; mi < 4; ++mi)
#pragma unroll
      for (int ni = 0; ni < 4; ++ni)
        acc[mi][ni] = __builtin_amdgcn_mfma_f32_16x16x32_bf16(af[mi], bfr[ni], acc[mi][ni], 0, 0, 0);
    __syncthreads();
  }

  if (z < 2) {
    unsigned short* Out = (z == 0) ? Qb : Kb;
    const float scale = (z == 0) ? 0.125f : 1.0f;   // fold 1/sqrt(64) into Q (exact pow2)
#pragma unroll
    for (int mi = 0; mi < 4; ++mi)
#pragma unroll
      for (int ni = 0; ni < 4; ++ni) {
        const int n = n0 + wc * 64 + ni * 16 + l15;
        const int mb = m0 + wr * 64 + mi * 16 + lg * 4;
#pragma unroll
        for (int r = 0; r < 4; ++r)
          Out[(size_t)(mb + r) * DIM + n] = f2bf(acc[mi][ni][r] * scale);
      }
  } else {
    // V stored head-transposed: Vt[(b*1024 + n)][s], b = m>>11, s = m&2047
#pragma unroll
    for (int mi = 0; mi < 4; ++mi)
#pragma unroll
      for (int ni = 0; ni < 4; ++ni) {
        const int n = n0 + wc * 64 + ni * 16 + l15;
        const int mb = m0 + wr * 64 + mi * 16 + lg * 4;
        const int b = mb >> 11, srow = mb & 2047;
        ushort4 v;
        v.x = f2bf(acc[mi][ni][0]); v.y = f2bf(acc[mi][ni][1]);
        v.z = f2bf(acc[mi][ni][2]); v.w = f2bf(acc[mi][ni][3]);
        *(ushort4*)&Vtb[((size_t)(b * 1024 + n)) * SEQ + srow] = v;
      }
  }
}

// ---- causal flash attention: block = (b,h,qtile of 64 rows), 4 waves x 16 rows ----
__global__ __launch_bounds__(256) void attn(const unsigned short* __restrict__ Qb,
                                            const unsigned short* __restrict__ Kb,
                                            const unsigned short* __restrict__ Vtb,
                                            unsigned short* __restrict__ Cb) {
  const int bh = blockIdx.x, qt = blockIdx.y;
  const int b = bh >> 4, h = bh & 15;
  const int lane = threadIdx.x & 63, wave = threadIdx.x >> 6;
  const int l15 = lane & 15, lg = lane >> 4;
  const int q0w = qt * 64 + wave * 16;
  __shared__ __align__(16) unsigned short Plds[4][16 * 40];  // per-wave P transpose buffer
  unsigned short* myP = &Plds[wave][0];

  const unsigned short* Qrow = Qb + (size_t)(b * SEQ + q0w + l15) * DIM + h * HDIM;
  const bf16x8 qf0 = *(const bf16x8*)&Qrow[lg * 8];
  const bf16x8 qf1 = *(const bf16x8*)&Qrow[32 + lg * 8];

  float m_r[4] = {-INFINITY, -INFINITY, -INFINITY, -INFINITY};
  float l_r[4] = {0.f, 0.f, 0.f, 0.f};
  f32x4 oacc[4] = {};
  const int qrow_base = q0w + lg * 4;
  const int kv_end = qt * 64 + 64;

  for (int kv0 = 0; kv0 < kv_end; kv0 += 32) {
    // scores S[q][kv] for 16q x 32kv: A=Q frag, B=K rows (K^T)
    f32x4 sc[2];
#pragma unroll
    for (int c = 0; c < 2; ++c) {
      const unsigned short* Krow = Kb + (size_t)(b * SEQ + kv0 + c * 16 + l15) * DIM + h * HDIM;
      bf16x8 kf0 = *(const bf16x8*)&Krow[lg * 8];
      bf16x8 kf1 = *(const bf16x8*)&Krow[32 + lg * 8];
      f32x4 t = {};
      t = __builtin_amdgcn_mfma_f32_16x16x32_bf16(qf0, kf0, t, 0, 0, 0);
      t = __builtin_amdgcn_mfma_f32_16x16x32_bf16(qf1, kf1, t, 0, 0, 0);
      sc[c] = t;
    }
    // causal mask (Q already scaled by 0.125)
#pragma unroll
    for (int c = 0; c < 2; ++c) {
      const int kv = kv0 + c * 16 + l15;
#pragma unroll
      for (int r = 0; r < 4; ++r)
        if (kv > qrow_base + r) sc[c][r] = -INFINITY;
    }
    // online softmax; row q = lg*4+r lives in the 16 lanes sharing lg
    float mx[4];
#pragma unroll
    for (int r = 0; r < 4; ++r) mx[r] = fmaxf(sc[0][r], sc[1][r]);
#pragma unroll
    for (int off = 1; off < 16; off <<= 1)
#pragma unroll
      for (int r = 0; r < 4; ++r) mx[r] = fmaxf(mx[r], __shfl_xor(mx[r], off));
    float alpha[4], p0[4], p1[4], ps[4];
#pragma unroll
    for (int r = 0; r < 4; ++r) {
      const float mn = fmaxf(m_r[r], mx[r]);   // finite from first tile (kv=0 always valid)
      alpha[r] = __expf(m_r[r] - mn);
      m_r[r] = mn;
      p0[r] = __expf(sc[0][r] - mn);
      p1[r] = __expf(sc[1][r] - mn);
      ps[r] = p0[r] + p1[r];
    }
#pragma unroll
    for (int off = 1; off < 16; off <<= 1)
#pragma unroll
      for (int r = 0; r < 4; ++r) ps[r] += __shfl_xor(ps[r], off);
#pragma unroll
    for (int r = 0; r < 4; ++r) l_r[r] = l_r[r] * alpha[r] + ps[r];
#pragma unroll
    for (int ni = 0; ni < 4; ++ni)
#pragma unroll
      for (int r = 0; r < 4; ++r) oacc[ni][r] *= alpha[r];

    // P (D-layout) -> LDS -> A-frag layout (stride 40 keeps 16B align + spreads banks)
#pragma unroll
    for (int r = 0; r < 4; ++r) {
      myP[(lg * 4 + r) * 40 + l15]      = f2bf(p0[r]);
      myP[(lg * 4 + r) * 40 + 16 + l15] = f2bf(p1[r]);
    }
    asm volatile("s_waitcnt lgkmcnt(0)" ::: "memory");
    __builtin_amdgcn_sched_barrier(0);
    const bf16x8 pf = *(const bf16x8*)&myP[l15 * 40 + lg * 8];

    // PV: B-frag = Vt rows (contiguous in kv)
    const unsigned short* Vbase = Vtb + (size_t)(b * 1024 + h * HDIM) * SEQ + kv0 + lg * 8;
#pragma unroll
    for (int ni = 0; ni < 4; ++ni) {
      bf16x8 vf = *(const bf16x8*)&Vbase[(size_t)(ni * 16 + l15) * SEQ];
      oacc[ni] = __builtin_amdgcn_mfma_f32_16x16x32_bf16(pf, vf, oacc[ni], 0, 0, 0);
    }
    asm volatile("" ::: "memory");  // keep next-iter P writes after this iter's P read
  }

  float rl[4];
#pragma unroll
  for (int r = 0; r < 4; ++r) rl[r] = 1.0f / l_r[r];
#pragma unroll
  for (int ni = 0; ni < 4; ++ni)
#pragma unroll
    for (int r = 0; r < 4; ++r) {
      const int t = q0w + lg * 4 + r;
      Cb[(size_t)(b * SEQ + t) * DIM + h * HDIM + ni * 16 + l15] = f2bf(oacc[ni][r] * rl[r]);
    }
}

// ---- output projection: out = Cb @ W_out^T(layout) + bias, fp32 out ----
__global__ __launch_bounds__(256) void gemm_out(const unsigned short* __restrict__ Cb,
                                                const unsigned short* __restrict__ WtO,
                                                const float* __restrict__ bias,
                                                float* __restrict__ out) {
  const int m0 = blockIdx.x * 128, n0 = blockIdx.y * 128;
  const int lane = threadIdx.x & 63, wave = threadIdx.x >> 6;
  const int wr = wave >> 1, wc = wave & 1;
  const int l15 = lane & 15, lg = lane >> 4;
  const int rowA = lane >> 2, colA = (lane & 3) * 8;
  const int sA = wave * 2;
  __shared__ __align__(16) unsigned short As[128 * 32], Bs[128 * 32];
  f32x4 acc[4][4] = {};

  for (int kt = 0; kt < DIM; kt += 32) {
    GLDS16(Cb  + (size_t)(m0 + (sA + 0) * 16 + rowA) * DIM + kt + colA, &As[(sA + 0) * 512]);
    GLDS16(Cb  + (size_t)(m0 + (sA + 1) * 16 + rowA) * DIM + kt + colA, &As[(sA + 1) * 512]);
    GLDS16(WtO + (size_t)(n0 + (sA + 0) * 16 + rowA) * DIM + kt + colA, &Bs[(sA + 0) * 512]);
    GLDS16(WtO + (size_t)(n0 + (sA + 1) * 16 + rowA) * DIM + kt + colA, &Bs[(sA + 1) * 512]);
    asm volatile("s_waitcnt vmcnt(0)" ::: "memory");
    __syncthreads();
    bf16x8 af[4], bfr[4];
#pragma unroll
    for (int mi = 0; mi < 4; ++mi)
      af[mi] = *(const bf16x8*)&As[(wr * 64 + mi * 16 + l15) * 32 + lg * 8];
#pragma unroll
    for (int ni = 0; ni < 4; ++ni)
      bfr[ni] = *(const bf16x8*)&Bs[(wc * 64 + ni * 16 + l15) * 32 + lg * 8];
#pragma unroll
    for (int mi = 0; mi < 4; ++mi)
#pragma unroll
      for (int ni = 0; ni < 4; ++ni)
        acc[mi][ni] = __builtin_amdgcn_mfma_f32_16x16x32_bf16(af[mi], bfr[ni], acc[mi][ni], 0, 0, 0);
    __syncthreads();
  }

#pragma unroll
  for (int ni = 0; ni < 4; ++ni) {
    const int n = n0 + wc * 64 + ni * 16 + l15;
    const float bv = bias[n];
#pragma unroll
    for (int mi = 0; mi < 4; ++mi) {
      const int mb = m0 + wr * 64 + mi * 16 + lg * 4;
#pragma unroll
      for (int r = 0; r < 4; ++r)
        out[(size_t)(mb + r) * DIM + n] = acc[mi][ni][r] + bv;
    }
  }
}

extern "C" void kernel_launch(void* const* d_in, const int* in_sizes, int n_in,
                              void* d_out, int out_size, void* d_ws, size_t ws_size,
                              hipStream_t stream) {
  const float* X  = (const float*)d_in[0];
  const float* WK = (const float*)d_in[1];
  const float* WQ = (const float*)d_in[2];
  const float* WV = (const float*)d_in[3];
  const float* WO = (const float*)d_in[4];
  const float* bo = (const float*)d_in[5];
  float* out = (float*)d_out;

  char* ws = (char*)d_ws;
  unsigned short* Xb    = (unsigned short*)(ws);                  // 16 MB (reused as Cb)
  unsigned short* WtAll = (unsigned short*)(ws + (16u << 20));    // 8 MB: Q,K,V,O transposed bf16
  unsigned short* Qb    = (unsigned short*)(ws + (24u << 20));    // 16 MB
  unsigned short* Kb    = (unsigned short*)(ws + (40u << 20));    // 16 MB
  unsigned short* Vtb   = (unsigned short*)(ws + (56u << 20));    // 16 MB
  unsigned short* Cb    = Xb;                                     // Xb dead after gemm_qkv

  convert_x<<<8192, 256, 0, stream>>>((const float4*)X, (ushort4*)Xb);
  transpose_w<<<dim3(32, 32, 4), dim3(32, 8), 0, stream>>>(WQ, WK, WV, WO, WtAll);
  gemm_qkv<<<dim3(64, 8, 3), 256, 0, stream>>>(Xb, WtAll, Qb, Kb, Vtb);
  attn<<<dim3(64, 32), 256, 0, stream>>>(Qb, Kb, Vtb, Cb);
  gemm_out<<<dim3(64, 8), 256, 0, stream>>>(Cb, WtAll + 3u * 1048576u, bo, out);
}

// Round 5
// 333.749 us; speedup vs baseline: 1.3660x; 1.3660x over previous
//
#include <hip/hip_runtime.h>

// Fused MHA: X[4,2048,1024] fp32; W_K,W_Q,W_V,W_out[1024,1024]; b_out[1024].
//   1. convert_x:  X fp32 -> Xb bf16
//   2. transpose_w: W* fp32 [k][n] -> Wt bf16 [n][k]
//   3. gemm_qkv:   Q (scaled by 0.125*log2e), K; V stored transposed Vt[b*1024+n][s]
//   4. attn:       swapped-operand flash attention (m214 structure), exp2 domain
//   5. gemm_out:   C @ W_out + b_out -> fp32 out

typedef float  f32x4  __attribute__((ext_vector_type(4)));
typedef float  f32x16 __attribute__((ext_vector_type(16)));
typedef __bf16 bf16x8 __attribute__((ext_vector_type(8)));
typedef unsigned int u32x4 __attribute__((ext_vector_type(4)));

#define DIM   1024
#define SEQ   2048
#define HDIM  64

static __device__ __forceinline__ unsigned short f2bf(float f) {
  unsigned int u = __builtin_bit_cast(unsigned int, f);
  u += 0x7fffu + ((u >> 16) & 1u);   // RNE
  return (unsigned short)(u >> 16);
}

static __device__ __forceinline__ float exp2a(float x) {
#if __has_builtin(__builtin_amdgcn_exp2f)
  return __builtin_amdgcn_exp2f(x);
#else
  return exp2f(x);
#endif
}

static __device__ __forceinline__ void pswap(unsigned& a, unsigned& b) {
#if __has_builtin(__builtin_amdgcn_permlane32_swap)
  auto r = __builtin_amdgcn_permlane32_swap(a, b, false, false);
  a = r[0]; b = r[1];
#else
  asm volatile("v_permlane32_swap_b32 %0, %1" : "+v"(a), "+v"(b));
#endif
}

#define CVTPK(lo_, hi_) ({ unsigned r_;                                                 \
  asm("v_cvt_pk_bf16_f32 %0, %1, %2" : "=v"(r_) : "v"(lo_), "v"(hi_)); r_; })

// async global->LDS, 16B per lane
#define GLDS16(g, l)                                                                    \
  __builtin_amdgcn_global_load_lds((__attribute__((address_space(1))) void*)(g),        \
                                   (__attribute__((address_space(3))) void*)(l), 16, 0, 0)

__global__ __launch_bounds__(256) void convert_x(const float4* __restrict__ X,
                                                 ushort4* __restrict__ Xb) {
  int i = blockIdx.x * 256 + threadIdx.x;
  float4 v = X[i];
  ushort4 o;
  o.x = f2bf(v.x); o.y = f2bf(v.y); o.z = f2bf(v.z); o.w = f2bf(v.w);
  Xb[i] = o;
}

__global__ __launch_bounds__(256) void transpose_w(const float* __restrict__ WQ,
                                                   const float* __restrict__ WK,
                                                   const float* __restrict__ WV,
                                                   const float* __restrict__ WO,
                                                   unsigned short* __restrict__ WtAll) {
  const int z = blockIdx.z;
  const float* W = (z == 0) ? WQ : (z == 1) ? WK : (z == 2) ? WV : WO;
  unsigned short* Wt = WtAll + (size_t)z * (DIM * DIM);
  __shared__ float tile[32][33];
  const int tx = threadIdx.x, ty = threadIdx.y;        // 32 x 8
  const int n0 = blockIdx.x * 32, k0 = blockIdx.y * 32;
#pragma unroll
  for (int r = 0; r < 4; ++r)
    tile[ty + 8 * r][tx] = W[(size_t)(k0 + ty + 8 * r) * DIM + n0 + tx];
  __syncthreads();
#pragma unroll
  for (int r = 0; r < 4; ++r)
    Wt[(size_t)(n0 + ty + 8 * r) * DIM + k0 + tx] = f2bf(tile[tx][ty + 8 * r]);
}

// ---- 128x128-tile bf16 GEMM (m97 structure), z selects Q/K/V ----
__global__ __launch_bounds__(256) void gemm_qkv(const unsigned short* __restrict__ Xb,
                                                const unsigned short* __restrict__ WtAll,
                                                unsigned short* __restrict__ Qb,
                                                unsigned short* __restrict__ Kb,
                                                unsigned short* __restrict__ Vtb) {
  const int z = blockIdx.z;
  const unsigned short* Wt = WtAll + (size_t)z * (DIM * DIM);
  const int m0 = blockIdx.x * 128, n0 = blockIdx.y * 128;
  const int lane = threadIdx.x & 63, wave = threadIdx.x >> 6;
  const int wr = wave >> 1, wc = wave & 1;
  const int l15 = lane & 15, lg = lane >> 4;
  const int rowA = lane >> 2, colA = (lane & 3) * 8;
  const int sA = wave * 2;
  __shared__ __align__(16) unsigned short As[128 * 32], Bs[128 * 32];
  f32x4 acc[4][4] = {};

  for (int kt = 0; kt < DIM; kt += 32) {
    GLDS16(Xb + (size_t)(m0 + (sA + 0) * 16 + rowA) * DIM + kt + colA, &As[(sA + 0) * 512]);
    GLDS16(Xb + (size_t)(m0 + (sA + 1) * 16 + rowA) * DIM + kt + colA, &As[(sA + 1) * 512]);
    GLDS16(Wt + (size_t)(n0 + (sA + 0) * 16 + rowA) * DIM + kt + colA, &Bs[(sA + 0) * 512]);
    GLDS16(Wt + (size_t)(n0 + (sA + 1) * 16 + rowA) * DIM + kt + colA, &Bs[(sA + 1) * 512]);
    asm volatile("s_waitcnt vmcnt(0)" ::: "memory");
    __syncthreads();
    bf16x8 af[4], bfr[4];
#pragma unroll
    for (int mi = 0; mi < 4; ++mi)
      af[mi] = *(const bf16x8*)&As[(wr * 64 + mi * 16 + l15) * 32 + lg * 8];
#pragma unroll
    for (int ni = 0; ni < 4; ++ni)
      bfr[ni] = *(const bf16x8*)&Bs[(wc * 64 + ni * 16 + l15) * 32 + lg * 8];
#pragma unroll
    for (int mi = 0; mi < 4; ++mi)
#pragma unroll
      for (int ni = 0; ni < 4; ++ni)
        acc[mi][ni] = __builtin_amdgcn_mfma_f32_16x16x32_bf16(af[mi], bfr[ni], acc[mi][ni], 0, 0, 0);
    __syncthreads();
  }

  if (z < 2) {
    unsigned short* Out = (z == 0) ? Qb : Kb;
    // Q folds 1/sqrt(64) AND log2(e): softmax runs in exp2 domain
    const float scale = (z == 0) ? (float)(0.125 * 1.4426950408889634) : 1.0f;
#pragma unroll
    for (int mi = 0; mi < 4; ++mi)
#pragma unroll
      for (int ni = 0; ni < 4; ++ni) {
        const int n = n0 + wc * 64 + ni * 16 + l15;
        const int mb = m0 + wr * 64 + mi * 16 + lg * 4;
#pragma unroll
        for (int r = 0; r < 4; ++r)
          Out[(size_t)(mb + r) * DIM + n] = f2bf(acc[mi][ni][r] * scale);
      }
  } else {
    // V stored head-transposed: Vt[(b*1024 + n)][s]
#pragma unroll
    for (int mi = 0; mi < 4; ++mi)
#pragma unroll
      for (int ni = 0; ni < 4; ++ni) {
        const int n = n0 + wc * 64 + ni * 16 + l15;
        const int mb = m0 + wr * 64 + mi * 16 + lg * 4;
        const int b = mb >> 11, srow = mb & 2047;
        ushort4 v;
        v.x = f2bf(acc[mi][ni][0]); v.y = f2bf(acc[mi][ni][1]);
        v.z = f2bf(acc[mi][ni][2]); v.w = f2bf(acc[mi][ni][3]);
        *(ushort4*)&Vtb[((size_t)(b * 1024 + n)) * SEQ + srow] = v;
      }
  }
}

// ---- swapped-operand causal flash attention (m214 structure) ----
// Block: 4 waves x 32 q-rows = 128 q. Per wave: lane owns q = q_base + (lane&31).
// S^T = K·Q^T (32x32x16 mfma): 32 P-values lane-local per 64-kv tile (with lane^32).
// PV swapped too: O^T = Vt·P^T, so m/l/alpha stay lane-local. No LDS, no barriers.
__global__ __launch_bounds__(256) void attn(const unsigned short* __restrict__ Qb,
                                            const unsigned short* __restrict__ Kb,
                                            const unsigned short* __restrict__ Vtb,
                                            unsigned short* __restrict__ Cb) {
  const int bh = blockIdx.x;
  const int qt = (gridDim.y - 1) - blockIdx.y;        // heavy q-tiles first
  const int b = bh >> 4, h = bh & 15;
  const int lane = threadIdx.x & 63, wave = threadIdx.x >> 6;
  const int l31 = lane & 31, hi = lane >> 5;
  const int q_base = qt * 128 + wave * 32;
  const int q = q_base + l31;

  // Q B-frags: lane holds col q, k-elems hi*8..+8 per 16-k step
  const unsigned short* Qp = Qb + (size_t)(b * SEQ + q) * DIM + h * HDIM + hi * 8;
  bf16x8 qf[4];
#pragma unroll
  for (int ks = 0; ks < 4; ++ks) qf[ks] = *(const bf16x8*)(Qp + ks * 16);

  float m_r = -INFINITY, l_r = 0.f;
  f32x16 o0 = {}, o1 = {};

  const unsigned short* Kbase = Kb + (size_t)(b * SEQ) * DIM + h * HDIM + hi * 8;
  const unsigned short* Vbase = Vtb + (size_t)(b * 1024 + h * HDIM + l31) * SEQ + hi * 8;
  const int n_tiles = (q_base + 32 + 63) >> 6;

  for (int t = 0; t < n_tiles; ++t) {
    const int kv0 = t << 6;
    // S^T[kv][q], two 32-kv halves
    f32x16 st0 = {}, st1 = {};
    __builtin_amdgcn_s_setprio(1);
#pragma unroll
    for (int ks = 0; ks < 4; ++ks) {
      bf16x8 kf0 = *(const bf16x8*)(Kbase + (size_t)(kv0 + l31) * DIM + ks * 16);
      bf16x8 kf1 = *(const bf16x8*)(Kbase + (size_t)(kv0 + 32 + l31) * DIM + ks * 16);
      st0 = __builtin_amdgcn_mfma_f32_32x32x16_bf16(kf0, qf[ks], st0, 0, 0, 0);
      st1 = __builtin_amdgcn_mfma_f32_32x32x16_bf16(kf1, qf[ks], st1, 0, 0, 0);
    }
    __builtin_amdgcn_s_setprio(0);

    // causal mask (diagonal tiles only); kv offset = (r&3)+8*(r>>2)+4*hi (+32 for st1)
    if (kv0 + 63 > q_base) {
      const int qm = q - kv0 - 4 * hi;
#pragma unroll
      for (int r = 0; r < 16; ++r) {
        const int c = (r & 3) + 8 * (r >> 2);
        if (c > qm)      st0[r] = -INFINITY;
        if (c + 32 > qm) st1[r] = -INFINITY;
      }
    }

    // lane-local row max (31 fmax) + partner half via one shfl
    float tmax = st0[0];
#pragma unroll
    for (int r = 1; r < 16; ++r) tmax = fmaxf(tmax, st0[r]);
#pragma unroll
    for (int r = 0; r < 16; ++r) tmax = fmaxf(tmax, st1[r]);
    tmax = fmaxf(tmax, __shfl_xor(tmax, 32));

    // defer-max (T13): skip rescale while tile max grows < 2^8
    if (__any(!(tmax <= m_r + 8.0f))) {
      const float mn = fmaxf(m_r, tmax);
      const float al = exp2a(m_r - mn);
      m_r = mn;
      l_r *= al;
      o0 *= al;
      o1 *= al;
    }

    // P = exp2(S - m), lane-local sum + one shfl
#pragma unroll
    for (int r = 0; r < 16; ++r) st0[r] = exp2a(st0[r] - m_r);
#pragma unroll
    for (int r = 0; r < 16; ++r) st1[r] = exp2a(st1[r] - m_r);
    float ps = 0.f;
#pragma unroll
    for (int r = 0; r < 16; ++r) ps += st0[r] + st1[r];
    ps += __shfl_xor(ps, 32);
    l_r += ps;

    // P -> bf16 B-frags via cvt_pk + permlane32_swap (T12): 16 cvt_pk + 8 swaps
    u32x4 pf[4];
    {
      unsigned a, bb;
      a = CVTPK(st0[0], st0[1]);  bb = CVTPK(st0[4], st0[5]);   pswap(a, bb); pf[0][0] = a; pf[0][2] = bb;
      a = CVTPK(st0[2], st0[3]);  bb = CVTPK(st0[6], st0[7]);   pswap(a, bb); pf[0][1] = a; pf[0][3] = bb;
      a = CVTPK(st0[8], st0[9]);  bb = CVTPK(st0[12], st0[13]); pswap(a, bb); pf[1][0] = a; pf[1][2] = bb;
      a = CVTPK(st0[10], st0[11]); bb = CVTPK(st0[14], st0[15]); pswap(a, bb); pf[1][1] = a; pf[1][3] = bb;
      a = CVTPK(st1[0], st1[1]);  bb = CVTPK(st1[4], st1[5]);   pswap(a, bb); pf[2][0] = a; pf[2][2] = bb;
      a = CVTPK(st1[2], st1[3]);  bb = CVTPK(st1[6], st1[7]);   pswap(a, bb); pf[2][1] = a; pf[2][3] = bb;
      a = CVTPK(st1[8], st1[9]);  bb = CVTPK(st1[12], st1[13]); pswap(a, bb); pf[3][0] = a; pf[3][2] = bb;
      a = CVTPK(st1[10], st1[11]); bb = CVTPK(st1[14], st1[15]); pswap(a, bb); pf[3][1] = a; pf[3][3] = bb;
    }

    // O^T += Vt · P^T  (A = Vt rows=d, contiguous 16B loads; B = P frags)
    const unsigned short* Vp = Vbase + kv0;
    __builtin_amdgcn_s_setprio(1);
#pragma unroll
    for (int ks = 0; ks < 4; ++ks) {
      bf16x8 v0 = *(const bf16x8*)(Vp + ks * 16);
      bf16x8 v1 = *(const bf16x8*)(Vp + (size_t)32 * SEQ + ks * 16);
      bf16x8 pb = __builtin_bit_cast(bf16x8, pf[ks]);
      o0 = __builtin_amdgcn_mfma_f32_32x32x16_bf16(v0, pb, o0, 0, 0, 0);
      o1 = __builtin_amdgcn_mfma_f32_32x32x16_bf16(v1, pb, o1, 0, 0, 0);
    }
    __builtin_amdgcn_s_setprio(0);
  }

  // write C row q: d = dhalf*32 + (r&3)+8*(r>>2)+4*hi  -> 4-contiguous groups
  const float rl = 1.0f / l_r;
  unsigned short* Co = Cb + (size_t)(b * SEQ + q) * DIM + h * HDIM;
#pragma unroll
  for (int j = 0; j < 4; ++j) {
    ushort4 w0, w1;
    w0.x = f2bf(o0[4 * j + 0] * rl); w0.y = f2bf(o0[4 * j + 1] * rl);
    w0.z = f2bf(o0[4 * j + 2] * rl); w0.w = f2bf(o0[4 * j + 3] * rl);
    w1.x = f2bf(o1[4 * j + 0] * rl); w1.y = f2bf(o1[4 * j + 1] * rl);
    w1.z = f2bf(o1[4 * j + 2] * rl); w1.w = f2bf(o1[4 * j + 3] * rl);
    *(ushort4*)(Co + 8 * j + 4 * hi) = w0;
    *(ushort4*)(Co + 32 + 8 * j + 4 * hi) = w1;
  }
}

// ---- output projection: out = Cb @ W_out + b_out, fp32 ----
__global__ __launch_bounds__(256) void gemm_out(const unsigned short* __restrict__ Cb,
                                                const unsigned short* __restrict__ WtO,
                                                const float* __restrict__ bias,
                                                float* __restrict__ out) {
  const int m0 = blockIdx.x * 128, n0 = blockIdx.y * 128;
  const int lane = threadIdx.x & 63, wave = threadIdx.x >> 6;
  const int wr = wave >> 1, wc = wave & 1;
  const int l15 = lane & 15, lg = lane >> 4;
  const int rowA = lane >> 2, colA = (lane & 3) * 8;
  const int sA = wave * 2;
  __shared__ __align__(16) unsigned short As[128 * 32], Bs[128 * 32];
  f32x4 acc[4][4] = {};

  for (int kt = 0; kt < DIM; kt += 32) {
    GLDS16(Cb  + (size_t)(m0 + (sA + 0) * 16 + rowA) * DIM + kt + colA, &As[(sA + 0) * 512]);
    GLDS16(Cb  + (size_t)(m0 + (sA + 1) * 16 + rowA) * DIM + kt + colA, &As[(sA + 1) * 512]);
    GLDS16(WtO + (size_t)(n0 + (sA + 0) * 16 + rowA) * DIM + kt + colA, &Bs[(sA + 0) * 512]);
    GLDS16(WtO + (size_t)(n0 + (sA + 1) * 16 + rowA) * DIM + kt + colA, &Bs[(sA + 1) * 512]);
    asm volatile("s_waitcnt vmcnt(0)" ::: "memory");
    __syncthreads();
    bf16x8 af[4], bfr[4];
#pragma unroll
    for (int mi = 0; mi < 4; ++mi)
      af[mi] = *(const bf16x8*)&As[(wr * 64 + mi * 16 + l15) * 32 + lg * 8];
#pragma unroll
    for (int ni = 0; ni < 4; ++ni)
      bfr[ni] = *(const bf16x8*)&Bs[(wc * 64 + ni * 16 + l15) * 32 + lg * 8];
#pragma unroll
    for (int mi = 0; mi < 4; ++mi)
#pragma unroll
      for (int ni = 0; ni < 4; ++ni)
        acc[mi][ni] = __builtin_amdgcn_mfma_f32_16x16x32_bf16(af[mi], bfr[ni], acc[mi][ni], 0, 0, 0);
    __syncthreads();
  }

#pragma unroll
  for (int ni = 0; ni < 4; ++ni) {
    const int n = n0 + wc * 64 + ni * 16 + l15;
    const float bv = bias[n];
#pragma unroll
    for (int mi = 0; mi < 4; ++mi) {
      const int mb = m0 + wr * 64 + mi * 16 + lg * 4;
#pragma unroll
      for (int r = 0; r < 4; ++r)
        out[(size_t)(mb + r) * DIM + n] = acc[mi][ni][r] + bv;
    }
  }
}

extern "C" void kernel_launch(void* const* d_in, const int* in_sizes, int n_in,
                              void* d_out, int out_size, void* d_ws, size_t ws_size,
                              hipStream_t stream) {
  const float* X  = (const float*)d_in[0];
  const float* WK = (const float*)d_in[1];
  const float* WQ = (const float*)d_in[2];
  const float* WV = (const float*)d_in[3];
  const float* WO = (const float*)d_in[4];
  const float* bo = (const float*)d_in[5];
  float* out = (float*)d_out;

  char* ws = (char*)d_ws;
  unsigned short* Xb    = (unsigned short*)(ws);                  // 16 MB (reused as Cb)
  unsigned short* WtAll = (unsigned short*)(ws + (16u << 20));    // 8 MB
  unsigned short* Qb    = (unsigned short*)(ws + (24u << 20));    // 16 MB
  unsigned short* Kb    = (unsigned short*)(ws + (40u << 20));    // 16 MB
  unsigned short* Vtb   = (unsigned short*)(ws + (56u << 20));    // 16 MB
  unsigned short* Cb    = Xb;

  convert_x<<<8192, 256, 0, stream>>>((const float4*)X, (ushort4*)Xb);
  transpose_w<<<dim3(32, 32, 4), dim3(32, 8), 0, stream>>>(WQ, WK, WV, WO, WtAll);
  gemm_qkv<<<dim3(64, 8, 3), 256, 0, stream>>>(Xb, WtAll, Qb, Kb, Vtb);
  attn<<<dim3(64, 16), 256, 0, stream>>>(Qb, Kb, Vtb, Cb);
  gemm_out<<<dim3(64, 8), 256, 0, stream>>>(Cb, WtAll + 3u * 1048576u, bo, out);
}

// Round 7
// 331.515 us; speedup vs baseline: 1.3752x; 1.0067x over previous
//
#include <hip/hip_runtime.h>

// Fused MHA: X[4,2048,1024] fp32; W_K,W_Q,W_V,W_out[1024,1024]; b_out[1024].
//   1. convert_x:  X fp32 -> Xb bf16
//   2. transpose_w: W* fp32 [k][n] -> Wt bf16 [n][k]
//   3. gemm_qkv:   Q (scaled by 0.125*log2e), K; V stored transposed Vt[b*1024+n][s]
//   4. attn:       swapped-operand flash attention, split-kv wave pairs + LDS merge
//   5. gemm_out:   C @ W_out + b_out -> fp32 out

typedef float  f32x4  __attribute__((ext_vector_type(4)));
typedef float  f32x16 __attribute__((ext_vector_type(16)));
typedef __bf16 bf16x8 __attribute__((ext_vector_type(8)));
typedef unsigned int u32x4 __attribute__((ext_vector_type(4)));

#define DIM   1024
#define SEQ   2048
#define HDIM  64

static __device__ __forceinline__ unsigned short f2bf(float f) {
  unsigned int u = __builtin_bit_cast(unsigned int, f);
  u += 0x7fffu + ((u >> 16) & 1u);   // RNE
  return (unsigned short)(u >> 16);
}

static __device__ __forceinline__ float exp2a(float x) {
#if __has_builtin(__builtin_amdgcn_exp2f)
  return __builtin_amdgcn_exp2f(x);
#else
  return exp2f(x);
#endif
}

static __device__ __forceinline__ void pswap(unsigned& a, unsigned& b) {
#if __has_builtin(__builtin_amdgcn_permlane32_swap)
  auto r = __builtin_amdgcn_permlane32_swap(a, b, false, false);
  a = r[0]; b = r[1];
#else
  asm volatile("v_permlane32_swap_b32 %0, %1" : "+v"(a), "+v"(b));
#endif
}

#define CVTPK(lo_, hi_) ({ unsigned r_;                                                 \
  asm("v_cvt_pk_bf16_f32 %0, %1, %2" : "=v"(r_) : "v"(lo_), "v"(hi_)); r_; })

// async global->LDS, 16B per lane
#define GLDS16(g, l)                                                                    \
  __builtin_amdgcn_global_load_lds((__attribute__((address_space(1))) void*)(g),        \
                                   (__attribute__((address_space(3))) void*)(l), 16, 0, 0)

__global__ __launch_bounds__(256) void convert_x(const float4* __restrict__ X,
                                                 ushort4* __restrict__ Xb) {
  int i = blockIdx.x * 256 + threadIdx.x;
  float4 v = X[i];
  ushort4 o;
  o.x = f2bf(v.x); o.y = f2bf(v.y); o.z = f2bf(v.z); o.w = f2bf(v.w);
  Xb[i] = o;
}

__global__ __launch_bounds__(256) void transpose_w(const float* __restrict__ WQ,
                                                   const float* __restrict__ WK,
                                                   const float* __restrict__ WV,
                                                   const float* __restrict__ WO,
                                                   unsigned short* __restrict__ WtAll) {
  const int z = blockIdx.z;
  const float* W = (z == 0) ? WQ : (z == 1) ? WK : (z == 2) ? WV : WO;
  unsigned short* Wt = WtAll + (size_t)z * (DIM * DIM);
  __shared__ float tile[32][33];
  const int tx = threadIdx.x, ty = threadIdx.y;        // 32 x 8
  const int n0 = blockIdx.x * 32, k0 = blockIdx.y * 32;
#pragma unroll
  for (int r = 0; r < 4; ++r)
    tile[ty + 8 * r][tx] = W[(size_t)(k0 + ty + 8 * r) * DIM + n0 + tx];
  __syncthreads();
#pragma unroll
  for (int r = 0; r < 4; ++r)
    Wt[(size_t)(n0 + ty + 8 * r) * DIM + k0 + tx] = f2bf(tile[tx][ty + 8 * r]);
}

// ---- 128x128-tile bf16 GEMM (m97 structure), z selects Q/K/V ----
__global__ __launch_bounds__(256) void gemm_qkv(const unsigned short* __restrict__ Xb,
                                                const unsigned short* __restrict__ WtAll,
                                                unsigned short* __restrict__ Qb,
                                                unsigned short* __restrict__ Kb,
                                                unsigned short* __restrict__ Vtb) {
  const int z = blockIdx.z;
  const unsigned short* Wt = WtAll + (size_t)z * (DIM * DIM);
  const int m0 = blockIdx.x * 128, n0 = blockIdx.y * 128;
  const int lane = threadIdx.x & 63, wave = threadIdx.x >> 6;
  const int wr = wave >> 1, wc = wave & 1;
  const int l15 = lane & 15, lg = lane >> 4;
  const int rowA = lane >> 2, colA = (lane & 3) * 8;
  const int sA = wave * 2;
  __shared__ __align__(16) unsigned short As[128 * 32], Bs[128 * 32];
  f32x4 acc[4][4] = {};

  for (int kt = 0; kt < DIM; kt += 32) {
    GLDS16(Xb + (size_t)(m0 + (sA + 0) * 16 + rowA) * DIM + kt + colA, &As[(sA + 0) * 512]);
    GLDS16(Xb + (size_t)(m0 + (sA + 1) * 16 + rowA) * DIM + kt + colA, &As[(sA + 1) * 512]);
    GLDS16(Wt + (size_t)(n0 + (sA + 0) * 16 + rowA) * DIM + kt + colA, &Bs[(sA + 0) * 512]);
    GLDS16(Wt + (size_t)(n0 + (sA + 1) * 16 + rowA) * DIM + kt + colA, &Bs[(sA + 1) * 512]);
    asm volatile("s_waitcnt vmcnt(0)" ::: "memory");
    __syncthreads();
    bf16x8 af[4], bfr[4];
#pragma unroll
    for (int mi = 0; mi < 4; ++mi)
      af[mi] = *(const bf16x8*)&As[(wr * 64 + mi * 16 + l15) * 32 + lg * 8];
#pragma unroll
    for (int ni = 0; ni < 4; ++ni)
      bfr[ni] = *(const bf16x8*)&Bs[(wc * 64 + ni * 16 + l15) * 32 + lg * 8];
#pragma unroll
    for (int mi = 0; mi < 4; ++mi)
#pragma unroll
      for (int ni = 0; ni < 4; ++ni)
        acc[mi][ni] = __builtin_amdgcn_mfma_f32_16x16x32_bf16(af[mi], bfr[ni], acc[mi][ni], 0, 0, 0);
    __syncthreads();
  }

  if (z < 2) {
    unsigned short* Out = (z == 0) ? Qb : Kb;
    // Q folds 1/sqrt(64) AND log2(e): softmax runs in exp2 domain
    const float scale = (z == 0) ? (float)(0.125 * 1.4426950408889634) : 1.0f;
#pragma unroll
    for (int mi = 0; mi < 4; ++mi)
#pragma unroll
      for (int ni = 0; ni < 4; ++ni) {
        const int n = n0 + wc * 64 + ni * 16 + l15;
        const int mb = m0 + wr * 64 + mi * 16 + lg * 4;
#pragma unroll
        for (int r = 0; r < 4; ++r)
          Out[(size_t)(mb + r) * DIM + n] = f2bf(acc[mi][ni][r] * scale);
      }
  } else {
    // V stored head-transposed: Vt[(b*1024 + n)][s]
#pragma unroll
    for (int mi = 0; mi < 4; ++mi)
#pragma unroll
      for (int ni = 0; ni < 4; ++ni) {
        const int n = n0 + wc * 64 + ni * 16 + l15;
        const int mb = m0 + wr * 64 + mi * 16 + lg * 4;
        const int b = mb >> 11, srow = mb & 2047;
        ushort4 v;
        v.x = f2bf(acc[mi][ni][0]); v.y = f2bf(acc[mi][ni][1]);
        v.z = f2bf(acc[mi][ni][2]); v.w = f2bf(acc[mi][ni][3]);
        *(ushort4*)&Vtb[((size_t)(b * 1024 + n)) * SEQ + srow] = v;
      }
  }
}

// ---- swapped-operand causal flash attention, split-kv wave pairs ----
// Block: 4 waves = 2 q-groups x 2 kv-splits over 64 q-rows. Wave (qg, sp):
// handles q = qt*64 + qg*32 + (lane&31); kv tiles t = sp, sp+2, ... (64 kv each).
// S^T = K·Q^T (32x32x16 mfma): P lane-local; O^T = Vt·P^T keeps m/l/alpha lane-local.
// End: odd wave dumps (m,l,O) to LDS; even wave merges and writes C.
__global__ __launch_bounds__(256) void attn(const unsigned short* __restrict__ Qb,
                                            const unsigned short* __restrict__ Kb,
                                            const unsigned short* __restrict__ Vtb,
                                            unsigned short* __restrict__ Cb) {
  const int bh = blockIdx.x;
  const int qt = (gridDim.y - 1) - blockIdx.y;        // heavy q-tiles first
  const int b = bh >> 4, h = bh & 15;
  const int lane = threadIdx.x & 63, wave = threadIdx.x >> 6;
  const int qg = wave >> 1, sp = wave & 1;
  const int l31 = lane & 31, hi = lane >> 5;
  const int q_base = qt * 64 + qg * 32;
  const int q = q_base + l31;

  // stride-35 rows: bank = (lane*3 + j) % 32 -> 2 lanes/bank (free, m136)
  __shared__ float Mrg[2][64][35];   // {m, l, o0[16], o1[16]}

  // Q B-frags: lane holds col q, k-elems hi*8..+8 per 16-k step
  const unsigned short* Qp = Qb + (size_t)(b * SEQ + q) * DIM + h * HDIM + hi * 8;
  bf16x8 qf[4];
#pragma unroll
  for (int ks = 0; ks < 4; ++ks) qf[ks] = *(const bf16x8*)(Qp + ks * 16);

  float m_r = -INFINITY, l_r = 0.f;
  f32x16 o0 = {}, o1 = {};

  const unsigned short* Kbase = Kb + (size_t)(b * SEQ) * DIM + h * HDIM + hi * 8;
  const unsigned short* Vbase = Vtb + (size_t)(b * 1024 + h * HDIM + l31) * SEQ + hi * 8;
  const int n_tiles = (q_base + 32 + 63) >> 6;

  for (int t = sp; t < n_tiles; t += 2) {
    const int kv0 = t << 6;
    // S^T[kv][q], two 32-kv halves
    f32x16 st0 = {}, st1 = {};
    __builtin_amdgcn_s_setprio(1);
#pragma unroll
    for (int ks = 0; ks < 4; ++ks) {
      bf16x8 kf0 = *(const bf16x8*)(Kbase + (size_t)(kv0 + l31) * DIM + ks * 16);
      bf16x8 kf1 = *(const bf16x8*)(Kbase + (size_t)(kv0 + 32 + l31) * DIM + ks * 16);
      st0 = __builtin_amdgcn_mfma_f32_32x32x16_bf16(kf0, qf[ks], st0, 0, 0, 0);
      st1 = __builtin_amdgcn_mfma_f32_32x32x16_bf16(kf1, qf[ks], st1, 0, 0, 0);
    }
    __builtin_amdgcn_s_setprio(0);

    // causal mask (diagonal tiles only); kv offset = (r&3)+8*(r>>2)+4*hi (+32 for st1)
    if (kv0 + 63 > q_base) {
      const int qm = q - kv0 - 4 * hi;
#pragma unroll
      for (int r = 0; r < 16; ++r) {
        const int c = (r & 3) + 8 * (r >> 2);
        if (c > qm)      st0[r] = -INFINITY;
        if (c + 32 > qm) st1[r] = -INFINITY;
      }
    }

    // lane-local row max (31 fmax) + partner half via one shfl
    float tmax = st0[0];
#pragma unroll
    for (int r = 1; r < 16; ++r) tmax = fmaxf(tmax, st0[r]);
#pragma unroll
    for (int r = 0; r < 16; ++r) tmax = fmaxf(tmax, st1[r]);
    tmax = fmaxf(tmax, __shfl_xor(tmax, 32));

    // defer-max (T13): skip rescale while tile max grows < 2^8
    if (__any(!(tmax <= m_r + 8.0f))) {
      const float mn = fmaxf(m_r, tmax);
      const float al = exp2a(m_r - mn);
      m_r = mn;
      l_r *= al;
      o0 *= al;
      o1 *= al;
    }

    // P = exp2(S - m), lane-local sum + one shfl
#pragma unroll
    for (int r = 0; r < 16; ++r) st0[r] = exp2a(st0[r] - m_r);
#pragma unroll
    for (int r = 0; r < 16; ++r) st1[r] = exp2a(st1[r] - m_r);
    float ps = 0.f;
#pragma unroll
    for (int r = 0; r < 16; ++r) ps += st0[r] + st1[r];
    ps += __shfl_xor(ps, 32);
    l_r += ps;

    // P -> bf16 B-frags via cvt_pk + permlane32_swap (T12): 16 cvt_pk + 8 swaps
    u32x4 pf[4];
    {
      unsigned a, bb;
      a = CVTPK(st0[0], st0[1]);  bb = CVTPK(st0[4], st0[5]);   pswap(a, bb); pf[0][0] = a; pf[0][2] = bb;
      a = CVTPK(st0[2], st0[3]);  bb = CVTPK(st0[6], st0[7]);   pswap(a, bb); pf[0][1] = a; pf[0][3] = bb;
      a = CVTPK(st0[8], st0[9]);  bb = CVTPK(st0[12], st0[13]); pswap(a, bb); pf[1][0] = a; pf[1][2] = bb;
      a = CVTPK(st0[10], st0[11]); bb = CVTPK(st0[14], st0[15]); pswap(a, bb); pf[1][1] = a; pf[1][3] = bb;
      a = CVTPK(st1[0], st1[1]);  bb = CVTPK(st1[4], st1[5]);   pswap(a, bb); pf[2][0] = a; pf[2][2] = bb;
      a = CVTPK(st1[2], st1[3]);  bb = CVTPK(st1[6], st1[7]);   pswap(a, bb); pf[2][1] = a; pf[2][3] = bb;
      a = CVTPK(st1[8], st1[9]);  bb = CVTPK(st1[12], st1[13]); pswap(a, bb); pf[3][0] = a; pf[3][2] = bb;
      a = CVTPK(st1[10], st1[11]); bb = CVTPK(st1[14], st1[15]); pswap(a, bb); pf[3][1] = a; pf[3][3] = bb;
    }

    // O^T += Vt · P^T  (A = Vt rows=d, contiguous 16B loads; B = P frags)
    const unsigned short* Vp = Vbase + kv0;
    __builtin_amdgcn_s_setprio(1);
#pragma unroll
    for (int ks = 0; ks < 4; ++ks) {
      bf16x8 v0 = *(const bf16x8*)(Vp + ks * 16);
      bf16x8 v1 = *(const bf16x8*)(Vp + (size_t)32 * SEQ + ks * 16);
      bf16x8 pb = __builtin_bit_cast(bf16x8, pf[ks]);
      o0 = __builtin_amdgcn_mfma_f32_32x32x16_bf16(v0, pb, o0, 0, 0, 0);
      o1 = __builtin_amdgcn_mfma_f32_32x32x16_bf16(v1, pb, o1, 0, 0, 0);
    }
    __builtin_amdgcn_s_setprio(0);
  }

  // ---- split-kv merge: odd wave publishes, even wave combines ----
  if (sp == 1) {
    float* row = &Mrg[qg][lane][0];
    row[0] = m_r; row[1] = l_r;
#pragma unroll
    for (int r = 0; r < 16; ++r) { row[2 + r] = o0[r]; row[18 + r] = o1[r]; }
  }
  __syncthreads();
  if (sp == 1) return;

  {
    const float* row = &Mrg[qg][lane][0];
    const float m1 = row[0], l1 = row[1];
    const float mn = fmaxf(m_r, m1);
    const float a0 = exp2a(m_r - mn), a1 = exp2a(m1 - mn);
    l_r = l_r * a0 + l1 * a1;
#pragma unroll
    for (int r = 0; r < 16; ++r) {
      o0[r] = o0[r] * a0 + row[2 + r] * a1;
      o1[r] = o1[r] * a0 + row[18 + r] * a1;
    }
  }

  // write C row q: d = dhalf*32 + (r&3)+8*(r>>2)+4*hi  -> 4-contiguous groups
  const float rl = 1.0f / l_r;
  unsigned short* Co = Cb + (size_t)(b * SEQ + q) * DIM + h * HDIM;
#pragma unroll
  for (int j = 0; j < 4; ++j) {
    ushort4 w0, w1;
    w0.x = f2bf(o0[4 * j + 0] * rl); w0.y = f2bf(o0[4 * j + 1] * rl);
    w0.z = f2bf(o0[4 * j + 2] * rl); w0.w = f2bf(o0[4 * j + 3] * rl);
    w1.x = f2bf(o1[4 * j + 0] * rl); w1.y = f2bf(o1[4 * j + 1] * rl);
    w1.z = f2bf(o1[4 * j + 2] * rl); w1.w = f2bf(o1[4 * j + 3] * rl);
    *(ushort4*)(Co + 8 * j + 4 * hi) = w0;
    *(ushort4*)(Co + 32 + 8 * j + 4 * hi) = w1;
  }
}

// ---- output projection: out = Cb @ W_out + b_out, fp32 ----
__global__ __launch_bounds__(256) void gemm_out(const unsigned short* __restrict__ Cb,
                                                const unsigned short* __restrict__ WtO,
                                                const float* __restrict__ bias,
                                                float* __restrict__ out) {
  const int m0 = blockIdx.x * 128, n0 = blockIdx.y * 128;
  const int lane = threadIdx.x & 63, wave = threadIdx.x >> 6;
  const int wr = wave >> 1, wc = wave & 1;
  const int l15 = lane & 15, lg = lane >> 4;
  const int rowA = lane >> 2, colA = (lane & 3) * 8;
  const int sA = wave * 2;
  __shared__ __align__(16) unsigned short As[128 * 32], Bs[128 * 32];
  f32x4 acc[4][4] = {};

  for (int kt = 0; kt < DIM; kt += 32) {
    GLDS16(Cb  + (size_t)(m0 + (sA + 0) * 16 + rowA) * DIM + kt + colA, &As[(sA + 0) * 512]);
    GLDS16(Cb  + (size_t)(m0 + (sA + 1) * 16 + rowA) * DIM + kt + colA, &As[(sA + 1) * 512]);
    GLDS16(WtO + (size_t)(n0 + (sA + 0) * 16 + rowA) * DIM + kt + colA, &Bs[(sA + 0) * 512]);
    GLDS16(WtO + (size_t)(n0 + (sA + 1) * 16 + rowA) * DIM + kt + colA, &Bs[(sA + 1) * 512]);
    asm volatile("s_waitcnt vmcnt(0)" ::: "memory");
    __syncthreads();
    bf16x8 af[4], bfr[4];
#pragma unroll
    for (int mi = 0; mi < 4; ++mi)
      af[mi] = *(const bf16x8*)&As[(wr * 64 + mi * 16 + l15) * 32 + lg * 8];
#pragma unroll
    for (int ni = 0; ni < 4; ++ni)
      bfr[ni] = *(const bf16x8*)&Bs[(wc * 64 + ni * 16 + l15) * 32 + lg * 8];
#pragma unroll
    for (int mi = 0; mi < 4; ++mi)
#pragma unroll
      for (int ni = 0; ni < 4; ++ni)
        acc[mi][ni] = __builtin_amdgcn_mfma_f32_16x16x32_bf16(af[mi], bfr[ni], acc[mi][ni], 0, 0, 0);
    __syncthreads();
  }

#pragma unroll
  for (int ni = 0; ni < 4; ++ni) {
    const int n = n0 + wc * 64 + ni * 16 + l15;
    const float bv = bias[n];
#pragma unroll
    for (int mi = 0; mi < 4; ++mi) {
      const int mb = m0 + wr * 64 + mi * 16 + lg * 4;
#pragma unroll
      for (int r = 0; r < 4; ++r)
        out[(size_t)(mb + r) * DIM + n] = acc[mi][ni][r] + bv;
    }
  }
}

extern "C" void kernel_launch(void* const* d_in, const int* in_sizes, int n_in,
                              void* d_out, int out_size, void* d_ws, size_t ws_size,
                              hipStream_t stream) {
  const float* X  = (const float*)d_in[0];
  const float* WK = (const float*)d_in[1];
  const float* WQ = (const float*)d_in[2];
  const float* WV = (const float*)d_in[3];
  const float* WO = (const float*)d_in[4];
  const float* bo = (const float*)d_in[5];
  float* out = (float*)d_out;

  char* ws = (char*)d_ws;
  unsigned short* Xb    = (unsigned short*)(ws);                  // 16 MB (reused as Cb)
  unsigned short* WtAll = (unsigned short*)(ws + (16u << 20));    // 8 MB
  unsigned short* Qb    = (unsigned short*)(ws + (24u << 20));    // 16 MB
  unsigned short* Kb    = (unsigned short*)(ws + (40u << 20));    // 16 MB
  unsigned short* Vtb   = (unsigned short*)(ws + (56u << 20));    // 16 MB
  unsigned short* Cb    = Xb;

  convert_x<<<8192, 256, 0, stream>>>((const float4*)X, (ushort4*)Xb);
  transpose_w<<<dim3(32, 32, 4), dim3(32, 8), 0, stream>>>(WQ, WK, WV, WO, WtAll);
  gemm_qkv<<<dim3(64, 8, 3), 256, 0, stream>>>(Xb, WtAll, Qb, Kb, Vtb);
  attn<<<dim3(64, 32), 256, 0, stream>>>(Qb, Kb, Vtb, Cb);
  gemm_out<<<dim3(64, 8), 256, 0, stream>>>(Cb, WtAll + 3u * 1048576u, bo, out);
}

// Round 8
// 261.706 us; speedup vs baseline: 1.7420x; 1.2667x over previous
//
#include <hip/hip_runtime.h>

// Fused MHA: X[4,2048,1024] fp32; W_K,W_Q,W_V,W_out[1024,1024]; b_out[1024].
//   1. convert_x:  X fp32 -> Xb bf16
//   2. transpose_w: W* fp32 [k][n] -> Wt bf16 [n][k]
//   3. gemm_qkv:   Q (scaled 0.125*log2e, layout [s][1024]);
//                  K head-major Kh[bh][s][64]; V tiled Vb[bh][t][d][s64]
//   4. attn:       swapped-operand flash attn; K/V tiles staged to LDS
//                  (coalesced global_load_lds, XOR-swizzled source), dbuf
//   5. gemm_out:   C @ W_out + b_out -> fp32 out

typedef float  f32x4  __attribute__((ext_vector_type(4)));
typedef float  f32x16 __attribute__((ext_vector_type(16)));
typedef __bf16 bf16x8 __attribute__((ext_vector_type(8)));
typedef unsigned int u32x4 __attribute__((ext_vector_type(4)));

#define DIM   1024
#define SEQ   2048
#define HDIM  64

static __device__ __forceinline__ unsigned short f2bf(float f) {
  unsigned int u = __builtin_bit_cast(unsigned int, f);
  u += 0x7fffu + ((u >> 16) & 1u);   // RNE
  return (unsigned short)(u >> 16);
}

static __device__ __forceinline__ float exp2a(float x) {
#if __has_builtin(__builtin_amdgcn_exp2f)
  return __builtin_amdgcn_exp2f(x);
#else
  return exp2f(x);
#endif
}

static __device__ __forceinline__ void pswap(unsigned& a, unsigned& b) {
#if __has_builtin(__builtin_amdgcn_permlane32_swap)
  auto r = __builtin_amdgcn_permlane32_swap(a, b, false, false);
  a = r[0]; b = r[1];
#else
  asm volatile("v_permlane32_swap_b32 %0, %1" : "+v"(a), "+v"(b));
#endif
}

#define CVTPK(lo_, hi_) ({ unsigned r_;                                                 \
  asm("v_cvt_pk_bf16_f32 %0, %1, %2" : "=v"(r_) : "v"(lo_), "v"(hi_)); r_; })

// async global->LDS, 16B per lane; lds dest = wave-uniform base + lane*16
#define GLDS16(g, l)                                                                    \
  __builtin_amdgcn_global_load_lds((__attribute__((address_space(1))) void*)(g),        \
                                   (__attribute__((address_space(3))) void*)(l), 16, 0, 0)

__global__ __launch_bounds__(256) void convert_x(const float4* __restrict__ X,
                                                 ushort4* __restrict__ Xb) {
  int i = blockIdx.x * 256 + threadIdx.x;
  float4 v = X[i];
  ushort4 o;
  o.x = f2bf(v.x); o.y = f2bf(v.y); o.z = f2bf(v.z); o.w = f2bf(v.w);
  Xb[i] = o;
}

__global__ __launch_bounds__(256) void transpose_w(const float* __restrict__ WQ,
                                                   const float* __restrict__ WK,
                                                   const float* __restrict__ WV,
                                                   const float* __restrict__ WO,
                                                   unsigned short* __restrict__ WtAll) {
  const int z = blockIdx.z;
  const float* W = (z == 0) ? WQ : (z == 1) ? WK : (z == 2) ? WV : WO;
  unsigned short* Wt = WtAll + (size_t)z * (DIM * DIM);
  __shared__ float tile[32][33];
  const int tx = threadIdx.x, ty = threadIdx.y;        // 32 x 8
  const int n0 = blockIdx.x * 32, k0 = blockIdx.y * 32;
#pragma unroll
  for (int r = 0; r < 4; ++r)
    tile[ty + 8 * r][tx] = W[(size_t)(k0 + ty + 8 * r) * DIM + n0 + tx];
  __syncthreads();
#pragma unroll
  for (int r = 0; r < 4; ++r)
    Wt[(size_t)(n0 + ty + 8 * r) * DIM + k0 + tx] = f2bf(tile[tx][ty + 8 * r]);
}

// ---- 128x128-tile bf16 GEMM (m97 structure), z selects Q/K/V ----
__global__ __launch_bounds__(256) void gemm_qkv(const unsigned short* __restrict__ Xb,
                                                const unsigned short* __restrict__ WtAll,
                                                unsigned short* __restrict__ Qb,
                                                unsigned short* __restrict__ Kh,
                                                unsigned short* __restrict__ Vb) {
  const int z = blockIdx.z;
  const unsigned short* Wt = WtAll + (size_t)z * (DIM * DIM);
  const int m0 = blockIdx.x * 128, n0 = blockIdx.y * 128;
  const int lane = threadIdx.x & 63, wave = threadIdx.x >> 6;
  const int wr = wave >> 1, wc = wave & 1;
  const int l15 = lane & 15, lg = lane >> 4;
  const int rowA = lane >> 2, colA = (lane & 3) * 8;
  const int sA = wave * 2;
  __shared__ __align__(16) unsigned short As[128 * 32], Bs[128 * 32];
  f32x4 acc[4][4] = {};

  for (int kt = 0; kt < DIM; kt += 32) {
    GLDS16(Xb + (size_t)(m0 + (sA + 0) * 16 + rowA) * DIM + kt + colA, &As[(sA + 0) * 512]);
    GLDS16(Xb + (size_t)(m0 + (sA + 1) * 16 + rowA) * DIM + kt + colA, &As[(sA + 1) * 512]);
    GLDS16(Wt + (size_t)(n0 + (sA + 0) * 16 + rowA) * DIM + kt + colA, &Bs[(sA + 0) * 512]);
    GLDS16(Wt + (size_t)(n0 + (sA + 1) * 16 + rowA) * DIM + kt + colA, &Bs[(sA + 1) * 512]);
    asm volatile("s_waitcnt vmcnt(0)" ::: "memory");
    __syncthreads();
    bf16x8 af[4], bfr[4];
#pragma unroll
    for (int mi = 0; mi < 4; ++mi)
      af[mi] = *(const bf16x8*)&As[(wr * 64 + mi * 16 + l15) * 32 + lg * 8];
#pragma unroll
    for (int ni = 0; ni < 4; ++ni)
      bfr[ni] = *(const bf16x8*)&Bs[(wc * 64 + ni * 16 + l15) * 32 + lg * 8];
#pragma unroll
    for (int mi = 0; mi < 4; ++mi)
#pragma unroll
      for (int ni = 0; ni < 4; ++ni)
        acc[mi][ni] = __builtin_amdgcn_mfma_f32_16x16x32_bf16(af[mi], bfr[ni], acc[mi][ni], 0, 0, 0);
    __syncthreads();
  }

  if (z == 0) {
    // Q folds 1/sqrt(64) AND log2(e): softmax runs in exp2 domain
    const float scale = (float)(0.125 * 1.4426950408889634);
#pragma unroll
    for (int mi = 0; mi < 4; ++mi)
#pragma unroll
      for (int ni = 0; ni < 4; ++ni) {
        const int n = n0 + wc * 64 + ni * 16 + l15;
        const int mb = m0 + wr * 64 + mi * 16 + lg * 4;
#pragma unroll
        for (int r = 0; r < 4; ++r)
          Qb[(size_t)(mb + r) * DIM + n] = f2bf(acc[mi][ni][r] * scale);
      }
  } else if (z == 1) {
    // K head-major: Kh[((b*16+h)*2048 + s)*64 + d]
#pragma unroll
    for (int mi = 0; mi < 4; ++mi)
#pragma unroll
      for (int ni = 0; ni < 4; ++ni) {
        const int n = n0 + wc * 64 + ni * 16 + l15;
        const int h = n >> 6, d = n & 63;
        const int mb = m0 + wr * 64 + mi * 16 + lg * 4;
        const int b = mb >> 11, s = mb & 2047;
        const size_t base = ((size_t)(b * 16 + h) * 2048 + s) * 64 + d;
#pragma unroll
        for (int r = 0; r < 4; ++r)
          Kh[base + (size_t)r * 64] = f2bf(acc[mi][ni][r]);
      }
  } else {
    // V tiled: Vb[(((b*16+h)*32 + t)*64 + d)*64 + si], t = s>>6, si = s&63
#pragma unroll
    for (int mi = 0; mi < 4; ++mi)
#pragma unroll
      for (int ni = 0; ni < 4; ++ni) {
        const int n = n0 + wc * 64 + ni * 16 + l15;
        const int h = n >> 6, d = n & 63;
        const int mb = m0 + wr * 64 + mi * 16 + lg * 4;
        const int b = mb >> 11, s = mb & 2047;
        const int t = s >> 6, si = s & 63;
        ushort4 v;
        v.x = f2bf(acc[mi][ni][0]); v.y = f2bf(acc[mi][ni][1]);
        v.z = f2bf(acc[mi][ni][2]); v.w = f2bf(acc[mi][ni][3]);
        *(ushort4*)&Vb[((((size_t)(b * 16 + h) * 32 + t) * 64 + d) * 64) + si] = v;
      }
  }
}

// ---- swapped-operand causal flash attention with LDS-staged K/V tiles ----
// Block: 4 waves x 32 q-rows = 128 q. All waves share each 64-kv tile, staged
// once per block into LDS (double-buffered). Staging: coalesced global_load_lds
// with XOR-pre-swizzled SOURCE (linear LDS dest, rule 21); fragment ds_read_b128
// uses the same swizzle -> no 32-way bank conflict (G4).
__global__ __launch_bounds__(256) void attn(const unsigned short* __restrict__ Qb,
                                            const unsigned short* __restrict__ Kh,
                                            const unsigned short* __restrict__ Vb,
                                            unsigned short* __restrict__ Cb) {
  const int bh = blockIdx.x;
  const int qt = (gridDim.y - 1) - blockIdx.y;        // heavy q-tiles first
  const int b = bh >> 4;
  const int tid = threadIdx.x;
  const int lane = tid & 63, wave = tid >> 6;
  const int l31 = lane & 31, hi = lane >> 5;
  const int swz = (l31 & 7) << 4;
  const int q_base = qt * 128 + wave * 32;
  const int q = q_base + l31;

  // [buf][ K: 0..8191 | V: 8192..16383 ], 8KB tile = 64 rows x 128B
  __shared__ __align__(16) char LDS[2][16384];

  // per-lane staging source offsets (bytes within an 8KB tile):
  // LDS linear pos L gets tile byte (row*128 + ((L&127) ^ ((row&7)<<4)))
  int soff0, soff1;
  {
    const int L0 = wave * 2048 + lane * 16;
    const int r0 = L0 >> 7;
    soff0 = r0 * 128 + ((L0 & 127) ^ ((r0 & 7) << 4));
    const int L1 = L0 + 1024;
    const int r1 = L1 >> 7;
    soff1 = r1 * 128 + ((L1 & 127) ^ ((r1 & 7) << 4));
  }
  const char* Kt0 = (const char*)Kh + ((size_t)bh * 2048) * 128;   // +t*8192 per tile
  const char* Vt0 = (const char*)Vb + ((size_t)bh * 32) * 8192;

  // Q B-frags: lane holds col q, k-elems hi*8..+8 per 16-k step
  const unsigned short* Qp = Qb + (size_t)(b * SEQ + q) * DIM + (bh & 15) * HDIM + hi * 8;
  bf16x8 qf[4];
#pragma unroll
  for (int ks = 0; ks < 4; ++ks) qf[ks] = *(const bf16x8*)(Qp + ks * 16);

  float m_r = -INFINITY, l_r = 0.f;
  f32x16 o0 = {}, o1 = {};

  const int n_tiles = 2 * qt + 2;
  int cur = 0;

  // prologue: stage tile 0
  {
    char* lK = &LDS[0][wave * 2048];
    char* lV = &LDS[0][8192 + wave * 2048];
    GLDS16(Kt0 + soff0, lK); GLDS16(Kt0 + soff1, lK + 1024);
    GLDS16(Vt0 + soff0, lV); GLDS16(Vt0 + soff1, lV + 1024);
  }
  __syncthreads();

  for (int t = 0; t < n_tiles; ++t) {
    const int kv0 = t << 6;
    // stage next tile into the other buffer (async; drains at syncthreads)
    if (t + 1 < n_tiles) {
      const char* kb = Kt0 + (size_t)(t + 1) * 8192;
      const char* vb = Vt0 + (size_t)(t + 1) * 8192;
      char* lK = &LDS[cur ^ 1][wave * 2048];
      char* lV = &LDS[cur ^ 1][8192 + wave * 2048];
      GLDS16(kb + soff0, lK); GLDS16(kb + soff1, lK + 1024);
      GLDS16(vb + soff0, lV); GLDS16(vb + soff1, lV + 1024);
    }

    if (kv0 <= q_base + 31) {   // wave-uniform: skip fully-masked tiles
      const char* Lb = &LDS[cur][0];
      // S^T[kv][q], two 32-kv halves
      f32x16 st0 = {}, st1 = {};
      __builtin_amdgcn_s_setprio(1);
#pragma unroll
      for (int ks = 0; ks < 4; ++ks) {
        const char* a = Lb + l31 * 128 + ((ks * 32 + hi * 16) ^ swz);
        bf16x8 kf0 = *(const bf16x8*)(a);
        bf16x8 kf1 = *(const bf16x8*)(a + 4096);
        st0 = __builtin_amdgcn_mfma_f32_32x32x16_bf16(kf0, qf[ks], st0, 0, 0, 0);
        st1 = __builtin_amdgcn_mfma_f32_32x32x16_bf16(kf1, qf[ks], st1, 0, 0, 0);
      }
      __builtin_amdgcn_s_setprio(0);

      // causal mask (diagonal tiles); kv offset = (r&3)+8*(r>>2)+4*hi (+32 st1)
      if (kv0 + 63 > q_base) {
        const int qm = q - kv0 - 4 * hi;
#pragma unroll
        for (int r = 0; r < 16; ++r) {
          const int c = (r & 3) + 8 * (r >> 2);
          if (c > qm)      st0[r] = -INFINITY;
          if (c + 32 > qm) st1[r] = -INFINITY;
        }
      }

      // lane-local row max + partner half via one shfl
      float tmax = st0[0];
#pragma unroll
      for (int r = 1; r < 16; ++r) tmax = fmaxf(tmax, st0[r]);
#pragma unroll
      for (int r = 0; r < 16; ++r) tmax = fmaxf(tmax, st1[r]);
      tmax = fmaxf(tmax, __shfl_xor(tmax, 32));

      // defer-max (T13)
      if (__any(!(tmax <= m_r + 8.0f))) {
        const float mn = fmaxf(m_r, tmax);
        const float al = exp2a(m_r - mn);
        m_r = mn;
        l_r *= al;
        o0 *= al;
        o1 *= al;
      }

      // P = exp2(S - m)
#pragma unroll
      for (int r = 0; r < 16; ++r) st0[r] = exp2a(st0[r] - m_r);
#pragma unroll
      for (int r = 0; r < 16; ++r) st1[r] = exp2a(st1[r] - m_r);
      float ps = 0.f;
#pragma unroll
      for (int r = 0; r < 16; ++r) ps += st0[r] + st1[r];
      ps += __shfl_xor(ps, 32);
      l_r += ps;

      // P -> bf16 B-frags via cvt_pk + permlane32_swap (T12)
      u32x4 pf[4];
      {
        unsigned a, bb;
        a = CVTPK(st0[0], st0[1]);   bb = CVTPK(st0[4], st0[5]);   pswap(a, bb); pf[0][0] = a; pf[0][2] = bb;
        a = CVTPK(st0[2], st0[3]);   bb = CVTPK(st0[6], st0[7]);   pswap(a, bb); pf[0][1] = a; pf[0][3] = bb;
        a = CVTPK(st0[8], st0[9]);   bb = CVTPK(st0[12], st0[13]); pswap(a, bb); pf[1][0] = a; pf[1][2] = bb;
        a = CVTPK(st0[10], st0[11]); bb = CVTPK(st0[14], st0[15]); pswap(a, bb); pf[1][1] = a; pf[1][3] = bb;
        a = CVTPK(st1[0], st1[1]);   bb = CVTPK(st1[4], st1[5]);   pswap(a, bb); pf[2][0] = a; pf[2][2] = bb;
        a = CVTPK(st1[2], st1[3]);   bb = CVTPK(st1[6], st1[7]);   pswap(a, bb); pf[2][1] = a; pf[2][3] = bb;
        a = CVTPK(st1[8], st1[9]);   bb = CVTPK(st1[12], st1[13]); pswap(a, bb); pf[3][0] = a; pf[3][2] = bb;
        a = CVTPK(st1[10], st1[11]); bb = CVTPK(st1[14], st1[15]); pswap(a, bb); pf[3][1] = a; pf[3][3] = bb;
      }

      // O^T += V · P^T  (A = V d-rows from LDS; B = P frags)
      __builtin_amdgcn_s_setprio(1);
#pragma unroll
      for (int ks = 0; ks < 4; ++ks) {
        const char* a = Lb + 8192 + l31 * 128 + ((ks * 32 + hi * 16) ^ swz);
        bf16x8 v0 = *(const bf16x8*)(a);
        bf16x8 v1 = *(const bf16x8*)(a + 4096);
        bf16x8 pb = __builtin_bit_cast(bf16x8, pf[ks]);
        o0 = __builtin_amdgcn_mfma_f32_32x32x16_bf16(v0, pb, o0, 0, 0, 0);
        o1 = __builtin_amdgcn_mfma_f32_32x32x16_bf16(v1, pb, o1, 0, 0, 0);
      }
      __builtin_amdgcn_s_setprio(0);
    }

    __syncthreads();   // drains this wave's GLDS16 (vmcnt) + orders buffer swap
    cur ^= 1;
  }

  // write C row q: d = dhalf*32 + (r&3)+8*(r>>2)+4*hi  -> 4-contiguous groups
  const float rl = 1.0f / l_r;
  unsigned short* Co = Cb + (size_t)(b * SEQ + q) * DIM + (bh & 15) * HDIM;
#pragma unroll
  for (int j = 0; j < 4; ++j) {
    ushort4 w0, w1;
    w0.x = f2bf(o0[4 * j + 0] * rl); w0.y = f2bf(o0[4 * j + 1] * rl);
    w0.z = f2bf(o0[4 * j + 2] * rl); w0.w = f2bf(o0[4 * j + 3] * rl);
    w1.x = f2bf(o1[4 * j + 0] * rl); w1.y = f2bf(o1[4 * j + 1] * rl);
    w1.z = f2bf(o1[4 * j + 2] * rl); w1.w = f2bf(o1[4 * j + 3] * rl);
    *(ushort4*)(Co + 8 * j + 4 * hi) = w0;
    *(ushort4*)(Co + 32 + 8 * j + 4 * hi) = w1;
  }
}

// ---- output projection: out = Cb @ W_out + b_out, fp32 ----
__global__ __launch_bounds__(256) void gemm_out(const unsigned short* __restrict__ Cb,
                                                const unsigned short* __restrict__ WtO,
                                                const float* __restrict__ bias,
                                                float* __restrict__ out) {
  const int m0 = blockIdx.x * 128, n0 = blockIdx.y * 128;
  const int lane = threadIdx.x & 63, wave = threadIdx.x >> 6;
  const int wr = wave >> 1, wc = wave & 1;
  const int l15 = lane & 15, lg = lane >> 4;
  const int rowA = lane >> 2, colA = (lane & 3) * 8;
  const int sA = wave * 2;
  __shared__ __align__(16) unsigned short As[128 * 32], Bs[128 * 32];
  f32x4 acc[4][4] = {};

  for (int kt = 0; kt < DIM; kt += 32) {
    GLDS16(Cb  + (size_t)(m0 + (sA + 0) * 16 + rowA) * DIM + kt + colA, &As[(sA + 0) * 512]);
    GLDS16(Cb  + (size_t)(m0 + (sA + 1) * 16 + rowA) * DIM + kt + colA, &As[(sA + 1) * 512]);
    GLDS16(WtO + (size_t)(n0 + (sA + 0) * 16 + rowA) * DIM + kt + colA, &Bs[(sA + 0) * 512]);
    GLDS16(WtO + (size_t)(n0 + (sA + 1) * 16 + rowA) * DIM + kt + colA, &Bs[(sA + 1) * 512]);
    asm volatile("s_waitcnt vmcnt(0)" ::: "memory");
    __syncthreads();
    bf16x8 af[4], bfr[4];
#pragma unroll
    for (int mi = 0; mi < 4; ++mi)
      af[mi] = *(const bf16x8*)&As[(wr * 64 + mi * 16 + l15) * 32 + lg * 8];
#pragma unroll
    for (int ni = 0; ni < 4; ++ni)
      bfr[ni] = *(const bf16x8*)&Bs[(wc * 64 + ni * 16 + l15) * 32 + lg * 8];
#pragma unroll
    for (int mi = 0; mi < 4; ++mi)
#pragma unroll
      for (int ni = 0; ni < 4; ++ni)
        acc[mi][ni] = __builtin_amdgcn_mfma_f32_16x16x32_bf16(af[mi], bfr[ni], acc[mi][ni], 0, 0, 0);
    __syncthreads();
  }

#pragma unroll
  for (int ni = 0; ni < 4; ++ni) {
    const int n = n0 + wc * 64 + ni * 16 + l15;
    const float bv = bias[n];
#pragma unroll
    for (int mi = 0; mi < 4; ++mi) {
      const int mb = m0 + wr * 64 + mi * 16 + lg * 4;
#pragma unroll
      for (int r = 0; r < 4; ++r)
        out[(size_t)(mb + r) * DIM + n] = acc[mi][ni][r] + bv;
    }
  }
}

extern "C" void kernel_launch(void* const* d_in, const int* in_sizes, int n_in,
                              void* d_out, int out_size, void* d_ws, size_t ws_size,
                              hipStream_t stream) {
  const float* X  = (const float*)d_in[0];
  const float* WK = (const float*)d_in[1];
  const float* WQ = (const float*)d_in[2];
  const float* WV = (const float*)d_in[3];
  const float* WO = (const float*)d_in[4];
  const float* bo = (const float*)d_in[5];
  float* out = (float*)d_out;

  char* ws = (char*)d_ws;
  unsigned short* Xb    = (unsigned short*)(ws);                  // 16 MB (reused as Cb)
  unsigned short* WtAll = (unsigned short*)(ws + (16u << 20));    // 8 MB
  unsigned short* Qb    = (unsigned short*)(ws + (24u << 20));    // 16 MB
  unsigned short* Kh    = (unsigned short*)(ws + (40u << 20));    // 16 MB head-major K
  unsigned short* Vb    = (unsigned short*)(ws + (56u << 20));    // 16 MB tiled V
  unsigned short* Cb    = Xb;

  convert_x<<<8192, 256, 0, stream>>>((const float4*)X, (ushort4*)Xb);
  transpose_w<<<dim3(32, 32, 4), dim3(32, 8), 0, stream>>>(WQ, WK, WV, WO, WtAll);
  gemm_qkv<<<dim3(64, 8, 3), 256, 0, stream>>>(Xb, WtAll, Qb, Kh, Vb);
  attn<<<dim3(64, 16), 256, 0, stream>>>(Qb, Kh, Vb, Cb);
  gemm_out<<<dim3(64, 8), 256, 0, stream>>>(Cb, WtAll + 3u * 1048576u, bo, out);
}